// Round 2
// baseline (538.017 us; speedup 1.0000x reference)
//
#include <hip/hip_runtime.h>
#include <cstdint>
#include <cstddef>

#define BATCH 2048
#define NZ 128
#define NGEN 8
#define SPB_FC 8                          // samples per FC block (same generator)
#define NBLK_FC (BATCH / SPB_FC + NGEN)   // 264: covers per-generator padding
#define H2_ELEMS 1792                     // 32*7*8 (x padded 7->8), bf16
#define WS_H2_OFF 16384                   // byte offset of h2 region in d_ws

typedef unsigned int u32;
typedef unsigned short u16;

__device__ __forceinline__ float lrelu(float x) { return fmaxf(x, 0.2f * x); }
__device__ __forceinline__ float bflo(u32 u) { union { u32 i; float f; } v; v.i = u << 16; return v.f; }
__device__ __forceinline__ float bfhi(u32 u) { union { u32 i; float f; } v; v.i = u & 0xffff0000u; return v.f; }
__device__ __forceinline__ float bf1(u16 u) { union { u32 i; float f; } v; v.i = ((u32)u) << 16; return v.f; }
__device__ __forceinline__ u16 f2bf(float f) {
    union { float f; u32 i; } v; v.f = f;
    u32 r = v.i + 0x7fffu + ((v.i >> 16) & 1u);   // round-to-nearest-even
    return (u16)(r >> 16);
}
__device__ __forceinline__ float fast_tanh(float x) {
    x = fminf(fmaxf(x, -9.f), 9.f);
    const float e = __expf(2.f * x);
    return (e - 1.f) / (e + 1.f);
}

// ---------------------------------------------------------------------------
// Kernel 1: bin samples by generator. wsi[0] = padded total;
// wsi[16..16+tot) = sample ids grouped by generator, groups padded to
// multiples of SPB_FC with -1.
// ---------------------------------------------------------------------------
__global__ void bin_kernel(const int* __restrict__ g_idx, int* __restrict__ wsi) {
    __shared__ int cnt[NGEN];
    __shared__ int pbase[NGEN + 1];
    __shared__ u16 rank[BATCH];
    const int tid = threadIdx.x;
    if (tid < NGEN) cnt[tid] = 0;
    __syncthreads();
    for (int b = tid; b < BATCH; b += 256) {
        int g = g_idx[b];
        rank[b] = (u16)atomicAdd(&cnt[g], 1);
    }
    __syncthreads();
    if (tid == 0) {
        int acc = 0;
        for (int g = 0; g < NGEN; ++g) {
            pbase[g] = acc;
            acc += ((cnt[g] + SPB_FC - 1) / SPB_FC) * SPB_FC;
        }
        pbase[NGEN] = acc;
        wsi[0] = acc;
    }
    __syncthreads();
    const int total = pbase[NGEN];
    for (int i = tid; i < total; i += 256) wsi[16 + i] = -1;
    __syncthreads();
    for (int b = tid; b < BATCH; b += 256) {
        int g = g_idx[b];
        wsi[16 + pbase[g] + (int)rank[b]] = b;
    }
}

// ---------------------------------------------------------------------------
// Kernel 2: FC1 + FC2 for SPB_FC samples sharing one generator.
// Writes h2 (post-lrelu) as bf16 in conv layout [b][ci 32][iy 7][ix pad 8].
// ---------------------------------------------------------------------------
__global__ __launch_bounds__(256) void fc_kernel(
    const float* __restrict__ z, const int* __restrict__ g_idx,
    const float* __restrict__ W1, const float* __restrict__ b1,
    const float* __restrict__ W2, const float* __restrict__ b2,
    const int* __restrict__ wsi, u16* __restrict__ h2g)
{
    __shared__ float zs[SPB_FC][NZ];          // 4 KB
    __shared__ float h1s[256][SPB_FC];        // 8 KB, k-major for b128 broadcast
    __shared__ int sb[SPB_FC];
    __shared__ int sV, sG;

    const int tid = threadIdx.x;
    const int base = blockIdx.x * SPB_FC;
    const int total = wsi[0];
    if (base >= total) return;

    if (tid == 0) {
        int v = 0;
        for (int s = 0; s < SPB_FC; ++s) {
            int e = wsi[16 + base + s];
            sb[s] = e;
            if (e >= 0) ++v;
        }
        sV = v;
        sG = g_idx[wsi[16 + base]];
    }
    __syncthreads();
    const int g = sG;
    const int V = sV;
    const float* W1g = W1 + g * (NZ * 256);
    const float* b1g = b1 + g * 256;
    const float* W2g = W2 + g * (256 * 1568);
    const float* b2g = b2 + g * 1568;

    for (int i = tid; i < SPB_FC * NZ; i += 256) {
        int s = i >> 7, k = i & 127;
        zs[s][k] = (s < V) ? z[(size_t)sb[s] * NZ + k] : 0.f;
    }
    __syncthreads();

    // FC1: h1[s][tid]
    {
        float acc[SPB_FC];
        const float bv = b1g[tid];
        #pragma unroll
        for (int s = 0; s < SPB_FC; ++s) acc[s] = bv;
        for (int k = 0; k < NZ; ++k) {
            const float w = W1g[k * 256 + tid];
            #pragma unroll
            for (int s = 0; s < SPB_FC; ++s) acc[s] += zs[s][k] * w;
        }
        #pragma unroll
        for (int s = 0; s < SPB_FC; ++s) h1s[tid][s] = lrelu(acc[s]);
    }
    __syncthreads();

    // FC2: thread covers cols {tid, tid+256, ..., tid+1536} (last only if tid<32)
    {
        float acc[7][SPB_FC];
        #pragma unroll
        for (int c = 0; c < 7; ++c)
            #pragma unroll
            for (int s = 0; s < SPB_FC; ++s) acc[c][s] = 0.f;
        const bool tail = (tid < 32);
        const float* wp = W2g + tid;
        for (int k = 0; k < 256; ++k) {
            float hv[SPB_FC];
            *(float4*)&hv[0] = *(const float4*)&h1s[k][0];
            *(float4*)&hv[4] = *(const float4*)&h1s[k][4];
            #pragma unroll
            for (int c = 0; c < 7; ++c) {
                const float w = (c < 6 || tail) ? wp[c * 256] : 0.f;
                #pragma unroll
                for (int s = 0; s < SPB_FC; ++s) acc[c][s] += hv[s] * w;
            }
            wp += 1568;
        }
        #pragma unroll
        for (int c = 0; c < 7; ++c) {
            const int j = tid + c * 256;
            if (j < 1568) {
                const float bv = b2g[j];
                const int ci = j / 49, rem = j % 49;
                const int iy = rem / 7, ix = rem % 7;
                const int off = ci * 56 + iy * 8 + ix;
                for (int s = 0; s < V; ++s)
                    h2g[(size_t)sb[s] * H2_ELEMS + off] = f2bf(lrelu(acc[c][s] + bv));
            }
        }
    }
}

// ---------------------------------------------------------------------------
// Kernel 3: all three transposed convs for ONE sample per block.
// Effective pad = 1 for all layers: 7 -> 14 -> 28 -> 28.
// out[co,y,x] = b[co] + sum in[ci,(y+1-a)/s,(x+1-c)/s] * w[ci,co,a,c]
// ---------------------------------------------------------------------------
__global__ __launch_bounds__(256, 4) void conv_kernel(
    const int* __restrict__ g_idx,
    const float* __restrict__ cw1, const float* __restrict__ cb1,
    const float* __restrict__ cw2, const float* __restrict__ cb2,
    const float* __restrict__ cw3, const float* __restrict__ cb3,
    const u16* __restrict__ h2g, float* __restrict__ out)
{
    __shared__ __align__(16) float h2s[32][7][8];   // 7 KB (fp32)
    __shared__ __align__(16) float c1s[16][14][16]; // 14 KB (fp32, x pad 14->16)
    __shared__ __align__(16) u16 c2s[8][28][28];    // 12.25 KB (bf16)
    __shared__ float w3s[72];

    const int tid = threadIdx.x;
    const int b = blockIdx.x;
    const int g = g_idx[b];
    const float* cw1g = cw1 + g * 8192;
    const float* cb1g = cb1 + g * 16;
    const float* cw2g = cw2 + g * 2048;
    const float* cb2g = cb2 + g * 8;
    const float* cw3g = cw3 + g * 72;
    const float  cb3v = cb3[g];

    // stage h2 (bf16 global -> fp32 LDS); 224 threads x 8 elements
    if (tid < 224) {
        const uint4 q = ((const uint4*)(h2g + (size_t)b * H2_ELEMS))[tid];
        float* hp = (float*)h2s + 8 * tid;
        ((float4*)hp)[0] = make_float4(bflo(q.x), bfhi(q.x), bflo(q.y), bfhi(q.y));
        ((float4*)hp)[1] = make_float4(bflo(q.z), bfhi(q.z), bflo(q.w), bfhi(q.w));
    }
    if (tid < 72) w3s[tid] = cw3g[tid];
    __syncthreads();

    // conv1: [32,7,7] -> [16,14,14], k=4, s=2
    if (tid < 224) {
        const int co = tid / 14, y = tid % 14;
        float acc[14];
        const float bv = cb1g[co];
        #pragma unroll
        for (int x = 0; x < 14; ++x) acc[x] = bv;
        const int a0 = (y + 1) & 1;
        for (int aa = 0; aa < 2; ++aa) {
            const int a = a0 + 2 * aa;
            const int iy = (y + 1 - a) >> 1;
            if ((unsigned)iy < 7u) {
                for (int ci = 0; ci < 32; ++ci) {
                    float rr[8];
                    *(float4*)&rr[0] = *(const float4*)&h2s[ci][iy][0];
                    *(float4*)&rr[4] = *(const float4*)&h2s[ci][iy][4];
                    const float4 w4 = *(const float4*)(cw1g + ci * 256 + co * 16 + a * 4);
                    const float wv[4] = {w4.x, w4.y, w4.z, w4.w};
                    #pragma unroll
                    for (int x = 0; x < 14; ++x) {
                        const int c0v = (x + 1) & 1;
                        const int ix0 = (x + 1 - c0v) >> 1;
                        if (ix0 < 7)  acc[x] += rr[ix0] * wv[c0v];
                        if (ix0 >= 1) acc[x] += rr[ix0 - 1] * wv[c0v + 2];
                    }
                }
            }
        }
        #pragma unroll
        for (int x = 0; x < 14; ++x) c1s[co][y][x] = lrelu(acc[x]);
    }
    __syncthreads();

    // conv2: [16,14,14] -> [8,28,28], k=4, s=2
    if (tid < 224) {
        const int co = tid / 28, y = tid % 28;
        float acc[28];
        const float bv = cb2g[co];
        #pragma unroll
        for (int x = 0; x < 28; ++x) acc[x] = bv;
        const int a0 = (y + 1) & 1;
        for (int aa = 0; aa < 2; ++aa) {
            const int a = a0 + 2 * aa;
            const int iy = (y + 1 - a) >> 1;
            if ((unsigned)iy < 14u) {
                for (int ci = 0; ci < 16; ++ci) {
                    float rr[16];
                    *(float4*)&rr[0]  = *(const float4*)&c1s[ci][iy][0];
                    *(float4*)&rr[4]  = *(const float4*)&c1s[ci][iy][4];
                    *(float4*)&rr[8]  = *(const float4*)&c1s[ci][iy][8];
                    *(float4*)&rr[12] = *(const float4*)&c1s[ci][iy][12];
                    const float4 w4 = *(const float4*)(cw2g + ci * 128 + co * 16 + a * 4);
                    const float wv[4] = {w4.x, w4.y, w4.z, w4.w};
                    #pragma unroll
                    for (int x = 0; x < 28; ++x) {
                        const int c0v = (x + 1) & 1;
                        const int ix0 = (x + 1 - c0v) >> 1;
                        if (ix0 < 14) acc[x] += rr[ix0] * wv[c0v];
                        if (ix0 >= 1) acc[x] += rr[ix0 - 1] * wv[c0v + 2];
                    }
                }
            }
        }
        u32* dst = (u32*)&c2s[co][y][0];
        #pragma unroll
        for (int xx = 0; xx < 14; ++xx) {
            const u32 lo = f2bf(lrelu(acc[2 * xx]));
            const u32 hi = f2bf(lrelu(acc[2 * xx + 1]));
            dst[xx] = lo | (hi << 16);
        }
    }
    __syncthreads();

    // conv3: [8,28,28] -> [1,28,28], k=3, s=1, tanh
    if (tid < 196) {
        const int y = tid / 7, q = tid % 7;
        const int xb = q * 4;
        float acc[4] = {cb3v, cb3v, cb3v, cb3v};
        for (int ci = 0; ci < 8; ++ci) {
            float wv[9];
            #pragma unroll
            for (int j = 0; j < 9; ++j) wv[j] = w3s[ci * 9 + j];
            #pragma unroll
            for (int a = 0; a < 3; ++a) {
                const int iy = y + 1 - a;
                if ((unsigned)iy < 28u) {
                    float rr[6];
                    #pragma unroll
                    for (int j = 0; j < 6; ++j) {
                        const int ix = xb - 1 + j;
                        rr[j] = ((unsigned)ix < 28u) ? bf1(c2s[ci][iy][ix]) : 0.f;
                    }
                    #pragma unroll
                    for (int xx = 0; xx < 4; ++xx)
                        #pragma unroll
                        for (int c = 0; c < 3; ++c)
                            acc[xx] += rr[xx + 2 - c] * wv[a * 3 + c];
                }
            }
        }
        float* op = out + (size_t)b * 784 + y * 28 + xb;
        #pragma unroll
        for (int xx = 0; xx < 4; ++xx) op[xx] = fast_tanh(acc[xx]);
    }
}

extern "C" void kernel_launch(void* const* d_in, const int* in_sizes, int n_in,
                              void* d_out, int out_size, void* d_ws, size_t ws_size,
                              hipStream_t stream) {
    const float* z   = (const float*)d_in[0];
    const int*   gi  = (const int*)d_in[1];
    const float* W1  = (const float*)d_in[2];
    const float* b1  = (const float*)d_in[3];
    const float* W2  = (const float*)d_in[4];
    const float* b2  = (const float*)d_in[5];
    const float* cw1 = (const float*)d_in[6];
    const float* cb1 = (const float*)d_in[7];
    const float* cw2 = (const float*)d_in[8];
    const float* cb2 = (const float*)d_in[9];
    const float* cw3 = (const float*)d_in[10];
    const float* cb3 = (const float*)d_in[11];
    int* wsi = (int*)d_ws;
    u16* h2g = (u16*)((char*)d_ws + WS_H2_OFF);

    bin_kernel<<<1, 256, 0, stream>>>(gi, wsi);
    fc_kernel<<<NBLK_FC, 256, 0, stream>>>(z, gi, W1, b1, W2, b2, wsi, h2g);
    conv_kernel<<<BATCH, 256, 0, stream>>>(gi, cw1, cb1, cw2, cb2, cw3, cb3,
                                           h2g, (float*)d_out);
}

// Round 3
// 314.222 us; speedup vs baseline: 1.7122x; 1.7122x over previous
//
#include <hip/hip_runtime.h>
#include <cstdint>
#include <cstddef>

#define BATCH 2048
#define NZ 128
#define NGEN 8
#define SPB_FC 4                          // samples per FC block (same generator)
#define NBLK_FC (BATCH / SPB_FC + NGEN)   // 520: covers per-generator padding
#define H2_ELEMS 1792                     // 32*7*8 (x padded 7->8), bf16
#define WS_H2_OFF 16384                   // byte offset of h2 region in d_ws

typedef unsigned int u32;
typedef unsigned short u16;

__device__ __forceinline__ float lrelu(float x) { return fmaxf(x, 0.2f * x); }
__device__ __forceinline__ float bflo(u32 u) { union { u32 i; float f; } v; v.i = u << 16; return v.f; }
__device__ __forceinline__ float bfhi(u32 u) { union { u32 i; float f; } v; v.i = u & 0xffff0000u; return v.f; }
__device__ __forceinline__ float bf1(u16 u) { union { u32 i; float f; } v; v.i = ((u32)u) << 16; return v.f; }
__device__ __forceinline__ u16 f2bf(float f) {
    union { float f; u32 i; } v; v.f = f;
    u32 r = v.i + 0x7fffu + ((v.i >> 16) & 1u);   // round-to-nearest-even
    return (u16)(r >> 16);
}
__device__ __forceinline__ float fast_tanh(float x) {
    x = fminf(fmaxf(x, -9.f), 9.f);
    const float e = __expf(2.f * x);
    return (e - 1.f) / (e + 1.f);
}

// ---------------------------------------------------------------------------
// Kernel 1: bin samples by generator. wsi[0] = padded total;
// wsi[16..16+tot) = sample ids grouped by generator, groups padded to
// multiples of SPB_FC with -1.
// ---------------------------------------------------------------------------
__global__ void bin_kernel(const int* __restrict__ g_idx, int* __restrict__ wsi) {
    __shared__ int cnt[NGEN];
    __shared__ int pbase[NGEN + 1];
    __shared__ u16 rank[BATCH];
    const int tid = threadIdx.x;
    if (tid < NGEN) cnt[tid] = 0;
    __syncthreads();
    for (int b = tid; b < BATCH; b += 256) {
        int g = g_idx[b];
        rank[b] = (u16)atomicAdd(&cnt[g], 1);
    }
    __syncthreads();
    if (tid == 0) {
        int acc = 0;
        for (int g = 0; g < NGEN; ++g) {
            pbase[g] = acc;
            acc += ((cnt[g] + SPB_FC - 1) / SPB_FC) * SPB_FC;
        }
        pbase[NGEN] = acc;
        wsi[0] = acc;
    }
    __syncthreads();
    const int total = pbase[NGEN];
    for (int i = tid; i < total; i += 256) wsi[16 + i] = -1;
    __syncthreads();
    for (int b = tid; b < BATCH; b += 256) {
        int g = g_idx[b];
        wsi[16 + pbase[g] + (int)rank[b]] = b;
    }
}

// ---------------------------------------------------------------------------
// Kernel 2: FC1 + FC2 for SPB_FC samples sharing one generator.
// Writes h2 (post-lrelu) as bf16 in conv layout [b][ci 32][iy 7][ix pad 8].
// Register budget kept low (acc[7][4]=28) so no spill is possible.
// ---------------------------------------------------------------------------
__global__ __launch_bounds__(256) void fc_kernel(
    const float* __restrict__ z, const int* __restrict__ g_idx,
    const float* __restrict__ W1, const float* __restrict__ b1,
    const float* __restrict__ W2, const float* __restrict__ b2,
    const int* __restrict__ wsi, u16* __restrict__ h2g)
{
    __shared__ float zs[SPB_FC][NZ];          // 2 KB
    __shared__ float h1s[256][SPB_FC];        // 4 KB, k-major for b128 broadcast
    __shared__ int sb[SPB_FC];
    __shared__ int sV, sG;

    const int tid = threadIdx.x;
    const int base = blockIdx.x * SPB_FC;
    const int total = wsi[0];
    if (base >= total) return;

    if (tid == 0) {
        int v = 0;
        for (int s = 0; s < SPB_FC; ++s) {
            int e = wsi[16 + base + s];
            sb[s] = e;
            if (e >= 0) ++v;
        }
        sV = v;
        sG = g_idx[wsi[16 + base]];   // first slot of a chunk is always valid
    }
    __syncthreads();
    const int g = sG;
    const int V = sV;
    const float* W1g = W1 + g * (NZ * 256);
    const float* b1g = b1 + g * 256;
    const float* W2g = W2 + g * (256 * 1568);
    const float* b2g = b2 + g * 1568;

    for (int i = tid; i < SPB_FC * NZ; i += 256) {
        int s = i >> 7, k = i & 127;
        zs[s][k] = (s < V) ? z[(size_t)sb[s] * NZ + k] : 0.f;
    }
    __syncthreads();

    // FC1
    {
        float acc[SPB_FC];
        const float bv = b1g[tid];
        #pragma unroll
        for (int s = 0; s < SPB_FC; ++s) acc[s] = bv;
        for (int k = 0; k < NZ; ++k) {
            const float w = W1g[k * 256 + tid];
            #pragma unroll
            for (int s = 0; s < SPB_FC; ++s) acc[s] += zs[s][k] * w;
        }
        #pragma unroll
        for (int s = 0; s < SPB_FC; ++s) h1s[tid][s] = lrelu(acc[s]);
    }
    __syncthreads();

    // FC2: thread covers cols {tid, tid+256, ..., tid+1536} (last only if tid<32)
    {
        float acc[7][SPB_FC];
        #pragma unroll
        for (int c = 0; c < 7; ++c)
            #pragma unroll
            for (int s = 0; s < SPB_FC; ++s) acc[c][s] = 0.f;
        const bool tail = (tid < 32);
        const float* wp = W2g + tid;
        for (int k = 0; k < 256; ++k) {
            float hv[SPB_FC];
            *(float4*)&hv[0] = *(const float4*)&h1s[k][0];
            #pragma unroll
            for (int c = 0; c < 7; ++c) {
                const float w = (c < 6 || tail) ? wp[c * 256] : 0.f;
                #pragma unroll
                for (int s = 0; s < SPB_FC; ++s) acc[c][s] += hv[s] * w;
            }
            wp += 1568;
        }
        #pragma unroll
        for (int c = 0; c < 7; ++c) {
            const int j = tid + c * 256;
            if (j < 1568) {
                const float bv = b2g[j];
                const int ci = j / 49, rem = j % 49;
                const int iy = rem / 7, ix = rem % 7;
                const int off = ci * 56 + iy * 8 + ix;
                for (int s = 0; s < V; ++s)
                    h2g[(size_t)sb[s] * H2_ELEMS + off] = f2bf(lrelu(acc[c][s] + bv));
            }
        }
    }
}

// ---------------------------------------------------------------------------
// conv2 half-pass: computes output x in [14*H, 14*H+14) for one (co,y) row.
// Peak live regs ~ acc[14]+rr[12] -> no spill possible.
// ---------------------------------------------------------------------------
template <int H>
__device__ __forceinline__ void conv2_half(
    const float (*c1s)[14][16], u16 (*c2s)[28][28],
    const float* cw2g, const float bv, const int co, const int y)
{
    float acc[14];
    #pragma unroll
    for (int xx = 0; xx < 14; ++xx) acc[xx] = bv;
    const int a0 = (y + 1) & 1;
    for (int aa = 0; aa < 2; ++aa) {
        const int a = a0 + 2 * aa;
        const int iy = (y + 1 - a) >> 1;
        if ((unsigned)iy < 14u) {
            for (int ci = 0; ci < 16; ++ci) {
                // rr[j] holds c1s value at ix = 4*H + j  (H=0: ix 0..7, H=1: ix 4..15)
                float rr[12];
                if (H == 0) {
                    *(float4*)&rr[0] = *(const float4*)&c1s[ci][iy][0];
                    *(float4*)&rr[4] = *(const float4*)&c1s[ci][iy][4];
                } else {
                    *(float4*)&rr[0] = *(const float4*)&c1s[ci][iy][4];
                    *(float4*)&rr[4] = *(const float4*)&c1s[ci][iy][8];
                    *(float4*)&rr[8] = *(const float4*)&c1s[ci][iy][12];
                }
                const float4 w4 = *(const float4*)(cw2g + ci * 128 + co * 16 + a * 4);
                const float wv[4] = {w4.x, w4.y, w4.z, w4.w};
                #pragma unroll
                for (int xx = 0; xx < 14; ++xx) {
                    const int x = 14 * H + xx;
                    const int c0v = (x + 1) & 1;
                    const int ix0 = (x + 1 - c0v) >> 1;
                    const int li = ix0 - 4 * H;            // compile-time constant
                    if (ix0 < 14) acc[xx] += rr[li] * wv[c0v];
                    if (ix0 >= 1) acc[xx] += rr[li - 1] * wv[c0v + 2];
                }
            }
        }
    }
    u32* dst = (u32*)&c2s[co][y][0];
    #pragma unroll
    for (int xx = 0; xx < 7; ++xx) {
        const u32 lo = f2bf(lrelu(acc[2 * xx]));
        const u32 hi = f2bf(lrelu(acc[2 * xx + 1]));
        dst[7 * H + xx] = lo | (hi << 16);
    }
}

// ---------------------------------------------------------------------------
// Kernel 3: all three transposed convs for ONE sample per block.
// 7 -> 14 -> 28 -> 28 (effective pad=1 everywhere).
// out[co,y,x] = b[co] + sum in[ci,(y+1-a)/s,(x+1-c)/s] * w[ci,co,a,c]
// ---------------------------------------------------------------------------
__global__ __launch_bounds__(256) void conv_kernel(
    const int* __restrict__ g_idx,
    const float* __restrict__ cw1, const float* __restrict__ cb1,
    const float* __restrict__ cw2, const float* __restrict__ cb2,
    const float* __restrict__ cw3, const float* __restrict__ cb3,
    const u16* __restrict__ h2g, float* __restrict__ out)
{
    __shared__ __align__(16) float h2s[32][7][8];   // 7 KB (fp32)
    __shared__ __align__(16) float c1s[16][14][16]; // 14 KB (fp32)
    __shared__ __align__(16) u16 c2s[8][28][28];    // 12.25 KB (bf16)
    __shared__ float w3s[72];

    const int tid = threadIdx.x;
    const int b = blockIdx.x;
    const int g = g_idx[b];
    const float* cw1g = cw1 + g * 8192;
    const float* cb1g = cb1 + g * 16;
    const float* cw2g = cw2 + g * 2048;
    const float* cb2g = cb2 + g * 8;
    const float* cw3g = cw3 + g * 72;
    const float  cb3v = cb3[g];

    // stage h2 (bf16 global -> fp32 LDS); 224 threads x 8 elements
    if (tid < 224) {
        const uint4 q = ((const uint4*)(h2g + (size_t)b * H2_ELEMS))[tid];
        float* hp = (float*)h2s + 8 * tid;
        ((float4*)hp)[0] = make_float4(bflo(q.x), bfhi(q.x), bflo(q.y), bfhi(q.y));
        ((float4*)hp)[1] = make_float4(bflo(q.z), bfhi(q.z), bflo(q.w), bfhi(q.w));
    }
    if (tid < 72) w3s[tid] = cw3g[tid];
    __syncthreads();

    // conv1: [32,7,7] -> [16,14,14], k=4, s=2
    if (tid < 224) {
        const int co = tid / 14, y = tid % 14;
        float acc[14];
        const float bv = cb1g[co];
        #pragma unroll
        for (int x = 0; x < 14; ++x) acc[x] = bv;
        const int a0 = (y + 1) & 1;
        for (int aa = 0; aa < 2; ++aa) {
            const int a = a0 + 2 * aa;
            const int iy = (y + 1 - a) >> 1;
            if ((unsigned)iy < 7u) {
                for (int ci = 0; ci < 32; ++ci) {
                    float rr[8];
                    *(float4*)&rr[0] = *(const float4*)&h2s[ci][iy][0];
                    *(float4*)&rr[4] = *(const float4*)&h2s[ci][iy][4];
                    const float4 w4 = *(const float4*)(cw1g + ci * 256 + co * 16 + a * 4);
                    const float wv[4] = {w4.x, w4.y, w4.z, w4.w};
                    #pragma unroll
                    for (int x = 0; x < 14; ++x) {
                        const int c0v = (x + 1) & 1;
                        const int ix0 = (x + 1 - c0v) >> 1;
                        if (ix0 < 7)  acc[x] += rr[ix0] * wv[c0v];
                        if (ix0 >= 1) acc[x] += rr[ix0 - 1] * wv[c0v + 2];
                    }
                }
            }
        }
        #pragma unroll
        for (int x = 0; x < 14; ++x) acc[x] = lrelu(acc[x]);
        // packed stores: fewer LDS access slots -> fewer bank-conflict cycles
        *(float4*)&c1s[co][y][0]  = *(float4*)&acc[0];
        *(float4*)&c1s[co][y][4]  = *(float4*)&acc[4];
        *(float4*)&c1s[co][y][8]  = *(float4*)&acc[8];
        *(float2*)&c1s[co][y][12] = *(float2*)&acc[12];
    }
    __syncthreads();

    // conv2: [16,14,14] -> [8,28,28], k=4, s=2 — two register-light half passes
    if (tid < 224) {
        const int co = tid / 28, y = tid % 28;
        const float bv = cb2g[co];
        conv2_half<0>(c1s, c2s, cw2g, bv, co, y);
        conv2_half<1>(c1s, c2s, cw2g, bv, co, y);
    }
    __syncthreads();

    // conv3: [8,28,28] -> [1,28,28], k=3, s=1, tanh
    if (tid < 196) {
        const int y = tid / 7, q = tid % 7;
        const int xb = q * 4;
        float acc[4] = {cb3v, cb3v, cb3v, cb3v};
        for (int ci = 0; ci < 8; ++ci) {
            float wv[9];
            #pragma unroll
            for (int j = 0; j < 9; ++j) wv[j] = w3s[ci * 9 + j];
            #pragma unroll
            for (int a = 0; a < 3; ++a) {
                const int iy = y + 1 - a;
                if ((unsigned)iy < 28u) {
                    float rr[6];
                    #pragma unroll
                    for (int j = 0; j < 6; ++j) {
                        const int ix = xb - 1 + j;
                        rr[j] = ((unsigned)ix < 28u) ? bf1(c2s[ci][iy][ix]) : 0.f;
                    }
                    #pragma unroll
                    for (int xx = 0; xx < 4; ++xx)
                        #pragma unroll
                        for (int c = 0; c < 3; ++c)
                            acc[xx] += rr[xx + 2 - c] * wv[a * 3 + c];
                }
            }
        }
        float* op = out + (size_t)b * 784 + y * 28 + xb;
        #pragma unroll
        for (int xx = 0; xx < 4; ++xx) op[xx] = fast_tanh(acc[xx]);
    }
}

extern "C" void kernel_launch(void* const* d_in, const int* in_sizes, int n_in,
                              void* d_out, int out_size, void* d_ws, size_t ws_size,
                              hipStream_t stream) {
    const float* z   = (const float*)d_in[0];
    const int*   gi  = (const int*)d_in[1];
    const float* W1  = (const float*)d_in[2];
    const float* b1  = (const float*)d_in[3];
    const float* W2  = (const float*)d_in[4];
    const float* b2  = (const float*)d_in[5];
    const float* cw1 = (const float*)d_in[6];
    const float* cb1 = (const float*)d_in[7];
    const float* cw2 = (const float*)d_in[8];
    const float* cb2 = (const float*)d_in[9];
    const float* cw3 = (const float*)d_in[10];
    const float* cb3 = (const float*)d_in[11];
    int* wsi = (int*)d_ws;
    u16* h2g = (u16*)((char*)d_ws + WS_H2_OFF);

    bin_kernel<<<1, 256, 0, stream>>>(gi, wsi);
    fc_kernel<<<NBLK_FC, 256, 0, stream>>>(z, gi, W1, b1, W2, b2, wsi, h2g);
    conv_kernel<<<BATCH, 256, 0, stream>>>(gi, cw1, cb1, cw2, cb2, cw3, cb3,
                                           h2g, (float*)d_out);
}

// Round 5
// 282.772 us; speedup vs baseline: 1.9027x; 1.1112x over previous
//
#include <hip/hip_runtime.h>
#include <cstdint>
#include <cstddef>

#define BATCH 2048
#define NZ 128
#define NGEN 8
#define GRPS 32                 // samples per fc group (same generator)
#define MAXG 72                 // max padded groups: ceil((2048+8*31)/32)
#define NT 7                    // fc2 col tiles of 224 (7*224 = 1568)
#define H2_ELEMS 1792           // 32*7*8 (x padded 7->8), bf16
#define WS_H2_OFF 16384         // byte offset of h2 region in d_ws

typedef unsigned int u32;
typedef unsigned short u16;

__device__ __forceinline__ float lrelu(float x) { return fmaxf(x, 0.2f * x); }
__device__ __forceinline__ float bflo(u32 u) { union { u32 i; float f; } v; v.i = u << 16; return v.f; }
__device__ __forceinline__ float bfhi(u32 u) { union { u32 i; float f; } v; v.i = u & 0xffff0000u; return v.f; }
__device__ __forceinline__ u16 f2bf(float f) {
    union { float f; u32 i; } v; v.f = f;
    u32 r = v.i + 0x7fffu + ((v.i >> 16) & 1u);   // round-to-nearest-even
    return (u16)(r >> 16);
}
__device__ __forceinline__ float fast_tanh(float x) {
    x = fminf(fmaxf(x, -9.f), 9.f);
    const float e = __expf(2.f * x);
    return (e - 1.f) / (e + 1.f);
}

// ---------------------------------------------------------------------------
// Kernel 1: bin samples by generator. wsi[0] = padded total;
// wsi[16..16+tot) = sample ids grouped by generator, groups padded to
// multiples of GRPS with -1.
// ---------------------------------------------------------------------------
__global__ void bin_kernel(const int* __restrict__ g_idx, int* __restrict__ wsi) {
    __shared__ int cnt[NGEN];
    __shared__ int pbase[NGEN + 1];
    __shared__ u16 rank[BATCH];
    const int tid = threadIdx.x;
    if (tid < NGEN) cnt[tid] = 0;
    __syncthreads();
    for (int b = tid; b < BATCH; b += 256) {
        int g = g_idx[b];
        rank[b] = (u16)atomicAdd(&cnt[g], 1);
    }
    __syncthreads();
    if (tid == 0) {
        int acc = 0;
        for (int g = 0; g < NGEN; ++g) {
            pbase[g] = acc;
            acc += ((cnt[g] + GRPS - 1) / GRPS) * GRPS;
        }
        pbase[NGEN] = acc;
        wsi[0] = acc;
    }
    __syncthreads();
    const int total = pbase[NGEN];
    for (int i = tid; i < total; i += 256) wsi[16 + i] = -1;
    __syncthreads();
    for (int b = tid; b < BATCH; b += 256) {
        int g = g_idx[b];
        wsi[16 + pbase[g] + (int)rank[b]] = b;
    }
}

// ---------------------------------------------------------------------------
// Kernel 2: fused FC1+FC2 grouped GEMM. Block = (group of 32 samples, one
// 224-wide FC2 col tile). Phase 1 recomputes h1[32][256] for the group
// (+50% FLOPs vs staging in ws, but self-contained). Phase 2 does the
// 32x224 (K=256) tile with 4-sample x 7-col register tiles.
// Writes h2 (post-lrelu) bf16 in conv layout [b][ci 32][iy 7][ix pad 8].
// ---------------------------------------------------------------------------
__global__ __launch_bounds__(256) void fc_kernel(
    const float* __restrict__ z, const int* __restrict__ g_idx,
    const float* __restrict__ W1, const float* __restrict__ b1,
    const float* __restrict__ W2, const float* __restrict__ b2,
    const int* __restrict__ wsi, u16* __restrict__ h2g)
{
    __shared__ float zs[GRPS][129];        // 16.1 KB, stride 129: conflict-free A reads
    __shared__ float h1s[256][GRPS + 1];   // 33 KB, stride 33: conflict-free A reads
    __shared__ int sb[GRPS];
    __shared__ int sG;

    const int tid = threadIdx.x;
    const int grp = blockIdx.x / NT;
    const int tile = blockIdx.x % NT;
    const int base = grp * GRPS;
    if (base >= wsi[0]) return;

    if (tid == 0) sG = g_idx[wsi[16 + base]];
    if (tid < GRPS) sb[tid] = wsi[16 + base + tid];
    __syncthreads();
    const int g = sG;
    const float* W1g = W1 + g * (NZ * 256);
    const float* b1g = b1 + g * 256;
    const float* W2g = W2 + g * (256 * 1568);
    const float* b2g = b2 + g * 1568;

    // stage z: float4 global read, scalar LDS writes (stride 129 unaligned for b128)
    for (int i4 = tid; i4 < GRPS * 32; i4 += 256) {
        const int s = i4 >> 5, f = i4 & 31;
        float4 v = make_float4(0.f, 0.f, 0.f, 0.f);
        if (sb[s] >= 0) v = *(const float4*)(z + (size_t)sb[s] * NZ + 4 * f);
        zs[s][4 * f + 0] = v.x; zs[s][4 * f + 1] = v.y;
        zs[s][4 * f + 2] = v.z; zs[s][4 * f + 3] = v.w;
    }
    __syncthreads();

    const int r  = tid & 7;    // sample group: samples 4r..4r+3
    const int cq = tid >> 3;   // col lane 0..31

    // ---------------- phase 1: FC1 -> h1s ----------------
    {
        float acc1[4][8];
        #pragma unroll
        for (int ds = 0; ds < 4; ++ds)
            #pragma unroll
            for (int jj = 0; jj < 8; ++jj) acc1[ds][jj] = 0.f;
        for (int k = 0; k < NZ; ++k) {
            float av[4];
            #pragma unroll
            for (int ds = 0; ds < 4; ++ds) av[ds] = zs[4 * r + ds][k];
            const float* wp = W1g + k * 256 + cq;
            #pragma unroll
            for (int jj = 0; jj < 8; ++jj) {
                const float w = wp[32 * jj];
                #pragma unroll
                for (int ds = 0; ds < 4; ++ds) acc1[ds][jj] += av[ds] * w;
            }
        }
        #pragma unroll
        for (int jj = 0; jj < 8; ++jj) {
            const int c = cq + 32 * jj;
            const float bv = b1g[c];
            #pragma unroll
            for (int ds = 0; ds < 4; ++ds)
                h1s[c][4 * r + ds] = lrelu(acc1[ds][jj] + bv);
        }
    }
    __syncthreads();

    // ---------------- phase 2: FC2 tile ----------------
    {
        float acc2[4][NT];
        #pragma unroll
        for (int ds = 0; ds < 4; ++ds)
            #pragma unroll
            for (int jj = 0; jj < NT; ++jj) acc2[ds][jj] = 0.f;
        const int col0 = tile * 224 + cq;
        for (int k = 0; k < 256; ++k) {
            float av[4];
            #pragma unroll
            for (int ds = 0; ds < 4; ++ds) av[ds] = h1s[k][4 * r + ds];
            const float* wp = W2g + k * 1568 + col0;
            #pragma unroll
            for (int jj = 0; jj < NT; ++jj) {
                const float w = wp[32 * jj];
                #pragma unroll
                for (int ds = 0; ds < 4; ++ds) acc2[ds][jj] += av[ds] * w;
            }
        }
        #pragma unroll
        for (int jj = 0; jj < NT; ++jj) {
            const int j = col0 + 32 * jj;
            const float bv = b2g[j];
            const int ci = j / 49, rem = j % 49;
            const int iy = rem / 7, ix = rem % 7;
            const int off = ci * 56 + iy * 8 + ix;
            #pragma unroll
            for (int ds = 0; ds < 4; ++ds) {
                const int bb = sb[4 * r + ds];
                if (bb >= 0)
                    h2g[(size_t)bb * H2_ELEMS + off] = f2bf(lrelu(acc2[ds][jj] + bv));
            }
        }
    }
}

// ---------------------------------------------------------------------------
// conv2 half-pass: output x in [14*H, 14*H+14) for one (co,y) row.
// Register-light by construction (acc[14]+rr[12]).
// ---------------------------------------------------------------------------
template <int H>
__device__ __forceinline__ void conv2_half(
    const float (*c1s)[14][20], float (*c2s)[28][29],
    const float* cw2g, const float bv, const int co, const int y)
{
    float acc[14];
    #pragma unroll
    for (int xx = 0; xx < 14; ++xx) acc[xx] = bv;
    const int a0 = (y + 1) & 1;
    for (int aa = 0; aa < 2; ++aa) {
        const int a = a0 + 2 * aa;
        const int iy = (y + 1 - a) >> 1;
        if ((unsigned)iy < 14u) {
            for (int ci = 0; ci < 16; ++ci) {
                // rr[j] = c1s[ci][iy][4*H + j]
                float rr[12];
                if (H == 0) {
                    *(float4*)&rr[0] = *(const float4*)&c1s[ci][iy][0];
                    *(float4*)&rr[4] = *(const float4*)&c1s[ci][iy][4];
                } else {
                    *(float4*)&rr[0] = *(const float4*)&c1s[ci][iy][4];
                    *(float4*)&rr[4] = *(const float4*)&c1s[ci][iy][8];
                    *(float4*)&rr[8] = *(const float4*)&c1s[ci][iy][12];
                }
                const float4 w4 = *(const float4*)(cw2g + ci * 128 + co * 16 + a * 4);
                const float wv[4] = {w4.x, w4.y, w4.z, w4.w};
                #pragma unroll
                for (int xx = 0; xx < 14; ++xx) {
                    const int x = 14 * H + xx;
                    const int c0v = (x + 1) & 1;
                    const int ix0 = (x + 1 - c0v) >> 1;
                    const int li = ix0 - 4 * H;            // compile-time constant
                    if (ix0 < 14) acc[xx] += rr[li] * wv[c0v];
                    if (ix0 >= 1) acc[xx] += rr[li - 1] * wv[c0v + 2];
                }
            }
        }
    }
    #pragma unroll
    for (int xx = 0; xx < 14; ++xx)
        c2s[co][y][14 * H + xx] = lrelu(acc[xx]);
}

// ---------------------------------------------------------------------------
// Kernel 3: all three transposed convs for ONE sample per block.
// 7 -> 14 -> 28 -> 28 (effective pad=1 everywhere).
// out[co,y,x] = b[co] + sum in[ci,(y+1-a)/s,(x+1-c)/s] * w[ci,co,a,c]
// LDS strides chosen for bank spread: c1s row=20 (8 distinct banks over iy),
// c2s row=29 (odd, prime-ish spread).
// ---------------------------------------------------------------------------
__global__ __launch_bounds__(256) void conv_kernel(
    const int* __restrict__ g_idx,
    const float* __restrict__ cw1, const float* __restrict__ cb1,
    const float* __restrict__ cw2, const float* __restrict__ cb2,
    const float* __restrict__ cw3, const float* __restrict__ cb3,
    const u16* __restrict__ h2g, float* __restrict__ out)
{
    __shared__ __align__(16) float h2s[32][7][8];   // 7 KB
    __shared__ __align__(16) float c1s[16][14][20]; // 17.5 KB
    __shared__ __align__(16) float c2s[8][28][29];  // 25.4 KB
    __shared__ float w3s[72];

    const int tid = threadIdx.x;
    const int b = blockIdx.x;
    const int g = g_idx[b];
    const float* cw1g = cw1 + g * 8192;
    const float* cb1g = cb1 + g * 16;
    const float* cw2g = cw2 + g * 2048;
    const float* cb2g = cb2 + g * 8;
    const float* cw3g = cw3 + g * 72;
    const float  cb3v = cb3[g];

    // stage h2 (bf16 global -> fp32 LDS); 224 threads x 8 elements
    if (tid < 224) {
        const uint4 q = ((const uint4*)(h2g + (size_t)b * H2_ELEMS))[tid];
        float* hp = (float*)h2s + 8 * tid;
        ((float4*)hp)[0] = make_float4(bflo(q.x), bfhi(q.x), bflo(q.y), bfhi(q.y));
        ((float4*)hp)[1] = make_float4(bflo(q.z), bfhi(q.z), bflo(q.w), bfhi(q.w));
    }
    if (tid < 72) w3s[tid] = cw3g[tid];
    __syncthreads();

    // conv1: [32,7,7] -> [16,14,14], k=4, s=2
    if (tid < 224) {
        const int co = tid / 14, y = tid % 14;
        float acc[14];
        const float bv = cb1g[co];
        #pragma unroll
        for (int x = 0; x < 14; ++x) acc[x] = bv;
        const int a0 = (y + 1) & 1;
        for (int aa = 0; aa < 2; ++aa) {
            const int a = a0 + 2 * aa;
            const int iy = (y + 1 - a) >> 1;
            if ((unsigned)iy < 7u) {
                for (int ci = 0; ci < 32; ++ci) {
                    float rr[8];
                    *(float4*)&rr[0] = *(const float4*)&h2s[ci][iy][0];
                    *(float4*)&rr[4] = *(const float4*)&h2s[ci][iy][4];
                    const float4 w4 = *(const float4*)(cw1g + ci * 256 + co * 16 + a * 4);
                    const float wv[4] = {w4.x, w4.y, w4.z, w4.w};
                    #pragma unroll
                    for (int x = 0; x < 14; ++x) {
                        const int c0v = (x + 1) & 1;
                        const int ix0 = (x + 1 - c0v) >> 1;
                        if (ix0 < 7)  acc[x] += rr[ix0] * wv[c0v];
                        if (ix0 >= 1) acc[x] += rr[ix0 - 1] * wv[c0v + 2];
                    }
                }
            }
        }
        #pragma unroll
        for (int x = 0; x < 14; ++x) acc[x] = lrelu(acc[x]);
        *(float4*)&c1s[co][y][0]  = *(float4*)&acc[0];
        *(float4*)&c1s[co][y][4]  = *(float4*)&acc[4];
        *(float4*)&c1s[co][y][8]  = *(float4*)&acc[8];
        *(float2*)&c1s[co][y][12] = *(float2*)&acc[12];
    }
    __syncthreads();

    // conv2: [16,14,14] -> [8,28,28], k=4, s=2 — two register-light half passes
    if (tid < 224) {
        const int co = tid / 28, y = tid % 28;
        const float bv = cb2g[co];
        conv2_half<0>(c1s, c2s, cw2g, bv, co, y);
        conv2_half<1>(c1s, c2s, cw2g, bv, co, y);
    }
    __syncthreads();

    // conv3: [8,28,28] -> [1,28,28], k=3, s=1, tanh
    if (tid < 196) {
        const int y = tid / 7, q = tid % 7;
        const int xb = q * 4;
        float acc[4] = {cb3v, cb3v, cb3v, cb3v};
        for (int ci = 0; ci < 8; ++ci) {
            float wv[9];
            #pragma unroll
            for (int j = 0; j < 9; ++j) wv[j] = w3s[ci * 9 + j];
            #pragma unroll
            for (int a = 0; a < 3; ++a) {
                const int iy = y + 1 - a;
                if ((unsigned)iy < 28u) {
                    float rr[6];
                    #pragma unroll
                    for (int j = 0; j < 6; ++j) {
                        const int ix = xb - 1 + j;
                        rr[j] = ((unsigned)ix < 28u) ? c2s[ci][iy][ix] : 0.f;
                    }
                    #pragma unroll
                    for (int xx = 0; xx < 4; ++xx)
                        #pragma unroll
                        for (int c = 0; c < 3; ++c)
                            acc[xx] += rr[xx + 2 - c] * wv[a * 3 + c];
                }
            }
        }
        float* op = out + (size_t)b * 784 + y * 28 + xb;
        #pragma unroll
        for (int xx = 0; xx < 4; ++xx) op[xx] = fast_tanh(acc[xx]);
    }
}

extern "C" void kernel_launch(void* const* d_in, const int* in_sizes, int n_in,
                              void* d_out, int out_size, void* d_ws, size_t ws_size,
                              hipStream_t stream) {
    const float* z   = (const float*)d_in[0];
    const int*   gi  = (const int*)d_in[1];
    const float* W1  = (const float*)d_in[2];
    const float* b1  = (const float*)d_in[3];
    const float* W2  = (const float*)d_in[4];
    const float* b2  = (const float*)d_in[5];
    const float* cw1 = (const float*)d_in[6];
    const float* cb1 = (const float*)d_in[7];
    const float* cw2 = (const float*)d_in[8];
    const float* cb2 = (const float*)d_in[9];
    const float* cw3 = (const float*)d_in[10];
    const float* cb3 = (const float*)d_in[11];
    int* wsi = (int*)d_ws;
    u16* h2g = (u16*)((char*)d_ws + WS_H2_OFF);

    bin_kernel<<<1, 256, 0, stream>>>(gi, wsi);
    fc_kernel<<<MAXG * NT, 256, 0, stream>>>(z, gi, W1, b1, W2, b2, wsi, h2g);
    conv_kernel<<<BATCH, 256, 0, stream>>>(gi, cw1, cb1, cw2, cb2, cw3, cb3,
                                           h2g, (float*)d_out);
}

// Round 6
// 228.939 us; speedup vs baseline: 2.3500x; 1.2351x over previous
//
#include <hip/hip_runtime.h>
#include <cstdint>
#include <cstddef>

#define BATCH 2048
#define NZ 128
#define NGEN 8
#define GRPS 32                 // samples per fc group (same generator)
#define MAXG 72                 // max padded groups: ceil((2048+8*31)/32)
#define NT 7                    // fc2 col tiles of 224 (7*224 = 1568)
#define H2_ELEMS 1792           // 32*7*8 (x padded 7->8), bf16
#define WS_H2_OFF 16384         // byte offset of h2 region in d_ws

typedef unsigned int u32;
typedef unsigned short u16;

__device__ __forceinline__ float lrelu(float x) { return fmaxf(x, 0.2f * x); }
__device__ __forceinline__ float bflo(u32 u) { union { u32 i; float f; } v; v.i = u << 16; return v.f; }
__device__ __forceinline__ float bfhi(u32 u) { union { u32 i; float f; } v; v.i = u & 0xffff0000u; return v.f; }
__device__ __forceinline__ float bf1(u16 u) { union { u32 i; float f; } v; v.i = ((u32)u) << 16; return v.f; }
__device__ __forceinline__ u16 f2bf(float f) {
    union { float f; u32 i; } v; v.f = f;
    u32 r = v.i + 0x7fffu + ((v.i >> 16) & 1u);   // round-to-nearest-even
    return (u16)(r >> 16);
}
__device__ __forceinline__ float fast_tanh(float x) {
    x = fminf(fmaxf(x, -9.f), 9.f);
    const float e = __expf(2.f * x);
    return (e - 1.f) / (e + 1.f);
}

// ---------------------------------------------------------------------------
// Kernel 1: bin samples by generator. wsi[0] = padded total;
// wsi[16..16+tot) = sample ids grouped by generator, groups padded to
// multiples of GRPS with -1.
// ---------------------------------------------------------------------------
__global__ void bin_kernel(const int* __restrict__ g_idx, int* __restrict__ wsi) {
    __shared__ int cnt[NGEN];
    __shared__ int pbase[NGEN + 1];
    __shared__ u16 rank[BATCH];
    const int tid = threadIdx.x;
    if (tid < NGEN) cnt[tid] = 0;
    __syncthreads();
    for (int b = tid; b < BATCH; b += 256) {
        int g = g_idx[b];
        rank[b] = (u16)atomicAdd(&cnt[g], 1);
    }
    __syncthreads();
    if (tid == 0) {
        int acc = 0;
        for (int g = 0; g < NGEN; ++g) {
            pbase[g] = acc;
            acc += ((cnt[g] + GRPS - 1) / GRPS) * GRPS;
        }
        pbase[NGEN] = acc;
        wsi[0] = acc;
    }
    __syncthreads();
    const int total = pbase[NGEN];
    for (int i = tid; i < total; i += 256) wsi[16 + i] = -1;
    __syncthreads();
    for (int b = tid; b < BATCH; b += 256) {
        int g = g_idx[b];
        wsi[16 + pbase[g] + (int)rank[b]] = b;
    }
}

// ---------------------------------------------------------------------------
// Kernel 2: fused FC1+FC2 grouped GEMM. Block = (group of 32 samples, one
// 224-wide FC2 col tile). Thread map: cq = tid&31 (contiguous cols ->
// 128 B/wave coalesced weight loads), r = tid>>5 (sample quad 4r..4r+3).
// z transposed in LDS (zst[k][s], stride 36) and h1 k-major (stride 36) so
// A-operand reads are aligned ds_read_b128.
// Writes h2 (post-lrelu) bf16 in conv layout [b][ci 32][iy 7][ix pad 8].
// ---------------------------------------------------------------------------
__global__ __launch_bounds__(256) void fc_kernel(
    const float* __restrict__ z, const int* __restrict__ g_idx,
    const float* __restrict__ W1, const float* __restrict__ b1,
    const float* __restrict__ W2, const float* __restrict__ b2,
    const int* __restrict__ wsi, u16* __restrict__ h2g)
{
    __shared__ float zst[NZ][36];          // 18 KB, [k][s] transposed
    __shared__ float h1s[256][36];         // 36.9 KB, [k][s]
    __shared__ int sb[GRPS];
    __shared__ int sG;

    const int tid = threadIdx.x;
    const int grp = blockIdx.x / NT;
    const int tile = blockIdx.x % NT;
    const int base = grp * GRPS;
    if (base >= wsi[0]) return;

    if (tid == 0) sG = g_idx[wsi[16 + base]];
    if (tid < GRPS) sb[tid] = wsi[16 + base + tid];
    __syncthreads();
    const int g = sG;
    const float* W1g = W1 + g * (NZ * 256);
    const float* b1g = b1 + g * 256;
    const float* W2g = W2 + g * (256 * 1568);
    const float* b2g = b2 + g * 1568;

    // stage z transposed: i4 -> (s = i4&31, f = i4>>5); lanes vary s so LDS
    // stores are conflict-free (bank = s + const).
    for (int i4 = tid; i4 < GRPS * 32; i4 += 256) {
        const int s = i4 & 31, f = i4 >> 5;
        float4 v = make_float4(0.f, 0.f, 0.f, 0.f);
        if (sb[s] >= 0) v = *(const float4*)(z + (size_t)sb[s] * NZ + 4 * f);
        zst[4 * f + 0][s] = v.x; zst[4 * f + 1][s] = v.y;
        zst[4 * f + 2][s] = v.z; zst[4 * f + 3][s] = v.w;
    }
    __syncthreads();

    const int cq = tid & 31;   // col lane 0..31 (wave-contiguous)
    const int r  = tid >> 5;   // sample quad: samples 4r..4r+3

    // ---------------- phase 1: FC1 -> h1s ----------------
    {
        float acc1[4][8];
        #pragma unroll
        for (int ds = 0; ds < 4; ++ds)
            #pragma unroll
            for (int jj = 0; jj < 8; ++jj) acc1[ds][jj] = 0.f;
        for (int k = 0; k < NZ; ++k) {
            float av[4];
            *(float4*)&av[0] = *(const float4*)&zst[k][4 * r];
            const float* wp = W1g + k * 256 + cq;
            #pragma unroll
            for (int jj = 0; jj < 8; ++jj) {
                const float w = wp[32 * jj];
                #pragma unroll
                for (int ds = 0; ds < 4; ++ds) acc1[ds][jj] += av[ds] * w;
            }
        }
        #pragma unroll
        for (int jj = 0; jj < 8; ++jj) {
            const int c = cq + 32 * jj;
            const float bv = b1g[c];
            float hv[4];
            #pragma unroll
            for (int ds = 0; ds < 4; ++ds) hv[ds] = lrelu(acc1[ds][jj] + bv);
            *(float4*)&h1s[c][4 * r] = *(float4*)&hv[0];
        }
    }
    __syncthreads();

    // ---------------- phase 2: FC2 tile ----------------
    {
        float acc2[4][NT];
        #pragma unroll
        for (int ds = 0; ds < 4; ++ds)
            #pragma unroll
            for (int jj = 0; jj < NT; ++jj) acc2[ds][jj] = 0.f;
        const int col0 = tile * 224 + cq;
        for (int k = 0; k < 256; ++k) {
            float av[4];
            *(float4*)&av[0] = *(const float4*)&h1s[k][4 * r];
            const float* wp = W2g + k * 1568 + col0;
            #pragma unroll
            for (int jj = 0; jj < NT; ++jj) {
                const float w = wp[32 * jj];
                #pragma unroll
                for (int ds = 0; ds < 4; ++ds) acc2[ds][jj] += av[ds] * w;
            }
        }
        #pragma unroll
        for (int jj = 0; jj < NT; ++jj) {
            const int j = col0 + 32 * jj;
            const float bv = b2g[j];
            const int ci = j / 49, rem = j % 49;
            const int iy = rem / 7, ix = rem % 7;
            const int off = ci * 56 + iy * 8 + ix;
            #pragma unroll
            for (int ds = 0; ds < 4; ++ds) {
                const int bb = sb[4 * r + ds];
                if (bb >= 0)
                    h2g[(size_t)bb * H2_ELEMS + off] = f2bf(lrelu(acc2[ds][jj] + bv));
            }
        }
    }
}

// ---------------------------------------------------------------------------
// conv2 half-pass: output x in [14*H, 14*H+14) for one (co,y) row.
// Register-light by construction (acc[14]+rr[12] per unrolled iter).
// ---------------------------------------------------------------------------
template <int H>
__device__ __forceinline__ void conv2_half(
    const float (*c1s)[14][20], u16 (*c2s)[28][30],
    const float* cw2g, const float bv, const int co, const int y)
{
    float acc[14];
    #pragma unroll
    for (int xx = 0; xx < 14; ++xx) acc[xx] = bv;
    const int a0 = (y + 1) & 1;
    for (int aa = 0; aa < 2; ++aa) {
        const int a = a0 + 2 * aa;
        const int iy = (y + 1 - a) >> 1;
        if ((unsigned)iy < 14u) {
            #pragma unroll 2
            for (int ci = 0; ci < 16; ++ci) {
                // rr[j] = c1s[ci][iy][4*H + j]
                float rr[12];
                if (H == 0) {
                    *(float4*)&rr[0] = *(const float4*)&c1s[ci][iy][0];
                    *(float4*)&rr[4] = *(const float4*)&c1s[ci][iy][4];
                } else {
                    *(float4*)&rr[0] = *(const float4*)&c1s[ci][iy][4];
                    *(float4*)&rr[4] = *(const float4*)&c1s[ci][iy][8];
                    *(float4*)&rr[8] = *(const float4*)&c1s[ci][iy][12];
                }
                const float4 w4 = *(const float4*)(cw2g + ci * 128 + co * 16 + a * 4);
                const float wv[4] = {w4.x, w4.y, w4.z, w4.w};
                #pragma unroll
                for (int xx = 0; xx < 14; ++xx) {
                    const int x = 14 * H + xx;
                    const int c0v = (x + 1) & 1;
                    const int ix0 = (x + 1 - c0v) >> 1;
                    const int li = ix0 - 4 * H;            // compile-time constant
                    if (ix0 < 14) acc[xx] += rr[li] * wv[c0v];
                    if (ix0 >= 1) acc[xx] += rr[li - 1] * wv[c0v + 2];
                }
            }
        }
    }
    u32* dst = (u32*)&c2s[co][y][0];
    #pragma unroll
    for (int xx = 0; xx < 7; ++xx) {
        const u32 lo = f2bf(lrelu(acc[2 * xx]));
        const u32 hi = f2bf(lrelu(acc[2 * xx + 1]));
        dst[7 * H + xx] = lo | (hi << 16);
    }
}

// ---------------------------------------------------------------------------
// Kernel 3: all three transposed convs for ONE sample per block.
// 7 -> 14 -> 28 -> 28 (effective pad=1 everywhere).
// out[co,y,x] = b[co] + sum in[ci,(y+1-a)/s,(x+1-c)/s] * w[ci,co,a,c]
// LDS aliasing: c2s (13.4 KB, live from conv2) overlaps h2s (7 KB, dead after
// conv1) — both at smem offset 0; the conv1->conv2 barrier orders them.
// Total LDS ~31.7 KB + launch_bounds(256,4) (VGPR<=128) -> 4 blocks/CU.
// ---------------------------------------------------------------------------
__global__ __launch_bounds__(256, 4) void conv_kernel(
    const int* __restrict__ g_idx,
    const float* __restrict__ cw1, const float* __restrict__ cb1,
    const float* __restrict__ cw2, const float* __restrict__ cb2,
    const float* __restrict__ cw3, const float* __restrict__ cb3,
    const u16* __restrict__ h2g, float* __restrict__ out)
{
    __shared__ __align__(16) char smem[13440 + 17920];  // 31.4 KB
    float (*h2s)[7][8]   = (float (*)[7][8])smem;       // [32][7][8], 7 KB
    u16  (*c2s)[28][30]  = (u16 (*)[28][30])smem;       // [8][28][30], 13.4 KB
    float (*c1s)[14][20] = (float (*)[14][20])(smem + 13440); // [16][14][20], 17.5 KB
    __shared__ float w3s[72];

    const int tid = threadIdx.x;
    const int b = blockIdx.x;
    const int g = g_idx[b];
    const float* cw1g = cw1 + g * 8192;
    const float* cb1g = cb1 + g * 16;
    const float* cw2g = cw2 + g * 2048;
    const float* cb2g = cb2 + g * 8;
    const float* cw3g = cw3 + g * 72;
    const float  cb3v = cb3[g];

    // stage h2 (bf16 global -> fp32 LDS); 224 threads x 8 elements
    if (tid < 224) {
        const uint4 q = ((const uint4*)(h2g + (size_t)b * H2_ELEMS))[tid];
        float* hp = (float*)h2s + 8 * tid;
        ((float4*)hp)[0] = make_float4(bflo(q.x), bfhi(q.x), bflo(q.y), bfhi(q.y));
        ((float4*)hp)[1] = make_float4(bflo(q.z), bfhi(q.z), bflo(q.w), bfhi(q.w));
    }
    if (tid < 72) w3s[tid] = cw3g[tid];
    __syncthreads();

    // conv1: [32,7,7] -> [16,14,14], k=4, s=2
    if (tid < 224) {
        const int co = tid / 14, y = tid % 14;
        float acc[14];
        const float bv = cb1g[co];
        #pragma unroll
        for (int x = 0; x < 14; ++x) acc[x] = bv;
        const int a0 = (y + 1) & 1;
        for (int aa = 0; aa < 2; ++aa) {
            const int a = a0 + 2 * aa;
            const int iy = (y + 1 - a) >> 1;
            if ((unsigned)iy < 7u) {
                #pragma unroll 2
                for (int ci = 0; ci < 32; ++ci) {
                    float rr[8];
                    *(float4*)&rr[0] = *(const float4*)&h2s[ci][iy][0];
                    *(float4*)&rr[4] = *(const float4*)&h2s[ci][iy][4];
                    const float4 w4 = *(const float4*)(cw1g + ci * 256 + co * 16 + a * 4);
                    const float wv[4] = {w4.x, w4.y, w4.z, w4.w};
                    #pragma unroll
                    for (int x = 0; x < 14; ++x) {
                        const int c0v = (x + 1) & 1;
                        const int ix0 = (x + 1 - c0v) >> 1;
                        if (ix0 < 7)  acc[x] += rr[ix0] * wv[c0v];
                        if (ix0 >= 1) acc[x] += rr[ix0 - 1] * wv[c0v + 2];
                    }
                }
            }
        }
        #pragma unroll
        for (int x = 0; x < 14; ++x) acc[x] = lrelu(acc[x]);
        *(float4*)&c1s[co][y][0]  = *(float4*)&acc[0];
        *(float4*)&c1s[co][y][4]  = *(float4*)&acc[4];
        *(float4*)&c1s[co][y][8]  = *(float4*)&acc[8];
        *(float2*)&c1s[co][y][12] = *(float2*)&acc[12];
    }
    __syncthreads();   // h2s dead beyond this point; c2s may now be written

    // conv2: [16,14,14] -> [8,28,28], k=4, s=2 — two register-light half passes
    if (tid < 224) {
        const int co = tid / 28, y = tid % 28;
        const float bv = cb2g[co];
        conv2_half<0>(c1s, c2s, cw2g, bv, co, y);
        conv2_half<1>(c1s, c2s, cw2g, bv, co, y);
    }
    __syncthreads();

    // conv3: [8,28,28] -> [1,28,28], k=3, s=1, tanh
    if (tid < 196) {
        const int y = tid / 7, q = tid % 7;
        const int xb = q * 4;
        float acc[4] = {cb3v, cb3v, cb3v, cb3v};
        for (int ci = 0; ci < 8; ++ci) {
            float wv[9];
            #pragma unroll
            for (int j = 0; j < 9; ++j) wv[j] = w3s[ci * 9 + j];
            #pragma unroll
            for (int a = 0; a < 3; ++a) {
                const int iy = y + 1 - a;
                if ((unsigned)iy < 28u) {
                    float rr[6];
                    #pragma unroll
                    for (int j = 0; j < 6; ++j) {
                        const int ix = xb - 1 + j;
                        rr[j] = ((unsigned)ix < 28u) ? bf1(c2s[ci][iy][ix]) : 0.f;
                    }
                    #pragma unroll
                    for (int xx = 0; xx < 4; ++xx)
                        #pragma unroll
                        for (int c = 0; c < 3; ++c)
                            acc[xx] += rr[xx + 2 - c] * wv[a * 3 + c];
                }
            }
        }
        float* op = out + (size_t)b * 784 + y * 28 + xb;
        #pragma unroll
        for (int xx = 0; xx < 4; ++xx) op[xx] = fast_tanh(acc[xx]);
    }
}

extern "C" void kernel_launch(void* const* d_in, const int* in_sizes, int n_in,
                              void* d_out, int out_size, void* d_ws, size_t ws_size,
                              hipStream_t stream) {
    const float* z   = (const float*)d_in[0];
    const int*   gi  = (const int*)d_in[1];
    const float* W1  = (const float*)d_in[2];
    const float* b1  = (const float*)d_in[3];
    const float* W2  = (const float*)d_in[4];
    const float* b2  = (const float*)d_in[5];
    const float* cw1 = (const float*)d_in[6];
    const float* cb1 = (const float*)d_in[7];
    const float* cw2 = (const float*)d_in[8];
    const float* cb2 = (const float*)d_in[9];
    const float* cw3 = (const float*)d_in[10];
    const float* cb3 = (const float*)d_in[11];
    int* wsi = (int*)d_ws;
    u16* h2g = (u16*)((char*)d_ws + WS_H2_OFF);

    bin_kernel<<<1, 256, 0, stream>>>(gi, wsi);
    fc_kernel<<<MAXG * NT, 256, 0, stream>>>(z, gi, W1, b1, W2, b2, wsi, h2g);
    conv_kernel<<<BATCH, 256, 0, stream>>>(gi, cw1, cb1, cw2, cb2, cw3, cb3,
                                           h2g, (float*)d_out);
}

// Round 7
// 227.749 us; speedup vs baseline: 2.3623x; 1.0052x over previous
//
#include <hip/hip_runtime.h>
#include <cstdint>
#include <cstddef>

#define BATCH 2048
#define NZ 128
#define NGEN 8
#define GRPS 32                 // samples per fc group (same generator)
#define MAXG 72                 // max padded groups: ceil((2048+8*31)/32)
#define NT 7                    // fc2 col tiles of 224 (7*224 = 1568)
#define KS 2                    // fc2 k-split: blocks per (group,tile)
#define H2_ELEMS 1792           // 32*7*8 (x padded 7->8) per sample, bf16
#define H2_HALF (BATCH * H2_ELEMS)   // elements per k-half partial array
#define WS_H2_OFF 16384         // byte offset of h2 region in d_ws

typedef unsigned int u32;
typedef unsigned short u16;

__device__ __forceinline__ float lrelu(float x) { return fmaxf(x, 0.2f * x); }
__device__ __forceinline__ float bflo(u32 u) { union { u32 i; float f; } v; v.i = u << 16; return v.f; }
__device__ __forceinline__ float bfhi(u32 u) { union { u32 i; float f; } v; v.i = u & 0xffff0000u; return v.f; }
__device__ __forceinline__ float bf1(u16 u) { union { u32 i; float f; } v; v.i = ((u32)u) << 16; return v.f; }
__device__ __forceinline__ u16 f2bf(float f) {
    union { float f; u32 i; } v; v.f = f;
    u32 r = v.i + 0x7fffu + ((v.i >> 16) & 1u);   // round-to-nearest-even
    return (u16)(r >> 16);
}
__device__ __forceinline__ float fast_tanh(float x) {
    x = fminf(fmaxf(x, -9.f), 9.f);
    const float e = __expf(2.f * x);
    return (e - 1.f) / (e + 1.f);
}

// ---------------------------------------------------------------------------
// Kernel 1: bin samples by generator. wsi[0] = padded total;
// wsi[16..16+tot) = sample ids grouped by generator, groups padded to
// multiples of GRPS with -1.
// ---------------------------------------------------------------------------
__global__ void bin_kernel(const int* __restrict__ g_idx, int* __restrict__ wsi) {
    __shared__ int cnt[NGEN];
    __shared__ int pbase[NGEN + 1];
    __shared__ u16 rank[BATCH];
    const int tid = threadIdx.x;
    if (tid < NGEN) cnt[tid] = 0;
    __syncthreads();
    for (int b = tid; b < BATCH; b += 256) {
        int g = g_idx[b];
        rank[b] = (u16)atomicAdd(&cnt[g], 1);
    }
    __syncthreads();
    if (tid == 0) {
        int acc = 0;
        for (int g = 0; g < NGEN; ++g) {
            pbase[g] = acc;
            acc += ((cnt[g] + GRPS - 1) / GRPS) * GRPS;
        }
        pbase[NGEN] = acc;
        wsi[0] = acc;
    }
    __syncthreads();
    const int total = pbase[NGEN];
    for (int i = tid; i < total; i += 256) wsi[16 + i] = -1;
    __syncthreads();
    for (int b = tid; b < BATCH; b += 256) {
        int g = g_idx[b];
        wsi[16 + pbase[g] + (int)rank[b]] = b;
    }
}

// ---------------------------------------------------------------------------
// Kernel 2: fused FC1+FC2 grouped GEMM with k-split. Block = (group of 32
// samples, 224-col FC2 tile, k-half). Phase 1 computes h1 cols
// [kh*128,(kh+1)*128) for the group; phase 2 accumulates the partial FC2 sum
// over those 128 k and writes a bf16 PARTIAL (no lrelu — applied in conv
// after the halves are summed). Bias folded into half 0.
// Grid = 72*7*2 = 1008 blocks (~4/CU); LDS 36.9 KB (4 blocks/CU fit).
// ---------------------------------------------------------------------------
__global__ __launch_bounds__(256) void fc_kernel(
    const float* __restrict__ z, const int* __restrict__ g_idx,
    const float* __restrict__ W1, const float* __restrict__ b1,
    const float* __restrict__ W2, const float* __restrict__ b2,
    const int* __restrict__ wsi, u16* __restrict__ h2g)
{
    __shared__ float zst[NZ][36];          // 18.4 KB, [k][s] transposed
    __shared__ float h1s[128][36];         // 18.4 KB, [local col][s]
    __shared__ int sb[GRPS];
    __shared__ int sG;

    const int tid = threadIdx.x;
    const int bx = blockIdx.x;
    const int grp = bx / (NT * KS);
    const int rem = bx % (NT * KS);
    const int tile = rem >> 1;
    const int kh = rem & 1;
    const int base = grp * GRPS;
    if (base >= wsi[0]) return;

    if (tid == 0) sG = g_idx[wsi[16 + base]];
    if (tid < GRPS) sb[tid] = wsi[16 + base + tid];
    __syncthreads();
    const int g = sG;
    const float* W1g = W1 + g * (NZ * 256);
    const float* b1g = b1 + g * 256;
    const float* W2g = W2 + g * (256 * 1568);
    const float* b2g = b2 + g * 1568;

    // stage z transposed: consecutive lanes read consecutive float4 of ONE
    // sample (coalesced 512 B per 32 lanes), scatter-store into zst[k][s].
    for (int i4 = tid; i4 < GRPS * 32; i4 += 256) {
        const int s = i4 >> 5, f = i4 & 31;
        float4 v = make_float4(0.f, 0.f, 0.f, 0.f);
        if (sb[s] >= 0) v = *(const float4*)(z + (size_t)sb[s] * NZ + 4 * f);
        zst[4 * f + 0][s] = v.x; zst[4 * f + 1][s] = v.y;
        zst[4 * f + 2][s] = v.z; zst[4 * f + 3][s] = v.w;
    }
    __syncthreads();

    const int cq = tid & 31;   // col lane 0..31 (wave-contiguous)
    const int r  = tid >> 5;   // sample quad: samples 4r..4r+3

    // ---------------- phase 1: FC1 cols [kh*128, kh*128+128) ----------------
    {
        float acc1[4][4];
        #pragma unroll
        for (int ds = 0; ds < 4; ++ds)
            #pragma unroll
            for (int jj = 0; jj < 4; ++jj) acc1[ds][jj] = 0.f;
        const float* W1h = W1g + kh * 128 + cq;
        #pragma unroll 2
        for (int k = 0; k < NZ; ++k) {
            float av[4];
            *(float4*)&av[0] = *(const float4*)&zst[k][4 * r];
            const float* wp = W1h + k * 256;
            #pragma unroll
            for (int jj = 0; jj < 4; ++jj) {
                const float w = wp[32 * jj];
                #pragma unroll
                for (int ds = 0; ds < 4; ++ds) acc1[ds][jj] += av[ds] * w;
            }
        }
        #pragma unroll
        for (int jj = 0; jj < 4; ++jj) {
            const int c = cq + 32 * jj;            // local col
            const float bv = b1g[kh * 128 + c];
            float hv[4];
            #pragma unroll
            for (int ds = 0; ds < 4; ++ds) hv[ds] = lrelu(acc1[ds][jj] + bv);
            *(float4*)&h1s[c][4 * r] = *(float4*)&hv[0];
        }
    }
    __syncthreads();

    // ---------------- phase 2: partial FC2 tile over 128 k ----------------
    {
        float acc2[4][NT];
        #pragma unroll
        for (int ds = 0; ds < 4; ++ds)
            #pragma unroll
            for (int jj = 0; jj < NT; ++jj) acc2[ds][jj] = 0.f;
        const int col0 = tile * 224 + cq;
        const float* W2h = W2g + (size_t)kh * 128 * 1568 + col0;
        #pragma unroll 4
        for (int kl = 0; kl < 128; ++kl) {
            float av[4];
            *(float4*)&av[0] = *(const float4*)&h1s[kl][4 * r];
            const float* wp = W2h + kl * 1568;
            #pragma unroll
            for (int jj = 0; jj < NT; ++jj) {
                const float w = wp[32 * jj];
                #pragma unroll
                for (int ds = 0; ds < 4; ++ds) acc2[ds][jj] += av[ds] * w;
            }
        }
        u16* h2h = h2g + (size_t)kh * H2_HALF;
        #pragma unroll
        for (int jj = 0; jj < NT; ++jj) {
            const int j = col0 + 32 * jj;
            const float bv = (kh == 0) ? b2g[j] : 0.f;   // bias in half 0 only
            const int ci = j / 49, rm = j % 49;
            const int iy = rm / 7, ix = rm % 7;
            const int off = ci * 56 + iy * 8 + ix;
            #pragma unroll
            for (int ds = 0; ds < 4; ++ds) {
                const int bb = sb[4 * r + ds];
                if (bb >= 0)
                    h2h[(size_t)bb * H2_ELEMS + off] = f2bf(acc2[ds][jj] + bv);
            }
        }
    }
}

// ---------------------------------------------------------------------------
// conv2 half-pass: output x in [14*H, 14*H+14) for one (co,y) row.
// Register-light by construction (acc[14]+rr[12] per unrolled iter).
// ---------------------------------------------------------------------------
template <int H>
__device__ __forceinline__ void conv2_half(
    const float (*c1s)[14][20], u16 (*c2s)[28][30],
    const float* cw2g, const float bv, const int co, const int y)
{
    float acc[14];
    #pragma unroll
    for (int xx = 0; xx < 14; ++xx) acc[xx] = bv;
    const int a0 = (y + 1) & 1;
    for (int aa = 0; aa < 2; ++aa) {
        const int a = a0 + 2 * aa;
        const int iy = (y + 1 - a) >> 1;
        if ((unsigned)iy < 14u) {
            #pragma unroll 2
            for (int ci = 0; ci < 16; ++ci) {
                // rr[j] = c1s[ci][iy][4*H + j]
                float rr[12];
                if (H == 0) {
                    *(float4*)&rr[0] = *(const float4*)&c1s[ci][iy][0];
                    *(float4*)&rr[4] = *(const float4*)&c1s[ci][iy][4];
                } else {
                    *(float4*)&rr[0] = *(const float4*)&c1s[ci][iy][4];
                    *(float4*)&rr[4] = *(const float4*)&c1s[ci][iy][8];
                    *(float4*)&rr[8] = *(const float4*)&c1s[ci][iy][12];
                }
                const float4 w4 = *(const float4*)(cw2g + ci * 128 + co * 16 + a * 4);
                const float wv[4] = {w4.x, w4.y, w4.z, w4.w};
                #pragma unroll
                for (int xx = 0; xx < 14; ++xx) {
                    const int x = 14 * H + xx;
                    const int c0v = (x + 1) & 1;
                    const int ix0 = (x + 1 - c0v) >> 1;
                    const int li = ix0 - 4 * H;            // compile-time constant
                    if (ix0 < 14) acc[xx] += rr[li] * wv[c0v];
                    if (ix0 >= 1) acc[xx] += rr[li - 1] * wv[c0v + 2];
                }
            }
        }
    }
    u32* dst = (u32*)&c2s[co][y][0];
    #pragma unroll
    for (int xx = 0; xx < 7; ++xx) {
        const u32 lo = f2bf(lrelu(acc[2 * xx]));
        const u32 hi = f2bf(lrelu(acc[2 * xx + 1]));
        dst[7 * H + xx] = lo | (hi << 16);
    }
}

// ---------------------------------------------------------------------------
// Kernel 3: all three transposed convs for ONE sample per block.
// Staging sums the two FC2 k-half partials and applies lrelu.
// 7 -> 14 -> 28 -> 28 (effective pad=1 everywhere).
// LDS aliasing: c2s overlaps h2s (dead after conv1). ~31.4 KB total.
// ---------------------------------------------------------------------------
__global__ __launch_bounds__(256, 4) void conv_kernel(
    const int* __restrict__ g_idx,
    const float* __restrict__ cw1, const float* __restrict__ cb1,
    const float* __restrict__ cw2, const float* __restrict__ cb2,
    const float* __restrict__ cw3, const float* __restrict__ cb3,
    const u16* __restrict__ h2g, float* __restrict__ out)
{
    __shared__ __align__(16) char smem[13440 + 17920];  // 31.4 KB
    float (*h2s)[7][8]   = (float (*)[7][8])smem;       // [32][7][8], 7 KB
    u16  (*c2s)[28][30]  = (u16 (*)[28][30])smem;       // [8][28][30], 13.4 KB
    float (*c1s)[14][20] = (float (*)[14][20])(smem + 13440); // [16][14][20], 17.5 KB
    __shared__ float w3s[72];

    const int tid = threadIdx.x;
    const int b = blockIdx.x;
    const int g = g_idx[b];
    const float* cw1g = cw1 + g * 8192;
    const float* cb1g = cb1 + g * 16;
    const float* cw2g = cw2 + g * 2048;
    const float* cb2g = cb2 + g * 8;
    const float* cw3g = cw3 + g * 72;
    const float  cb3v = cb3[g];

    // stage h2: sum bf16 k-half partials, lrelu, fp32 LDS. 224 thr x 8 elems
    if (tid < 224) {
        const uint4 qa = ((const uint4*)(h2g + (size_t)b * H2_ELEMS))[tid];
        const uint4 qb = ((const uint4*)(h2g + (size_t)H2_HALF + (size_t)b * H2_ELEMS))[tid];
        float* hp = (float*)h2s + 8 * tid;
        hp[0] = lrelu(bflo(qa.x) + bflo(qb.x));
        hp[1] = lrelu(bfhi(qa.x) + bfhi(qb.x));
        hp[2] = lrelu(bflo(qa.y) + bflo(qb.y));
        hp[3] = lrelu(bfhi(qa.y) + bfhi(qb.y));
        hp[4] = lrelu(bflo(qa.z) + bflo(qb.z));
        hp[5] = lrelu(bfhi(qa.z) + bfhi(qb.z));
        hp[6] = lrelu(bflo(qa.w) + bflo(qb.w));
        hp[7] = lrelu(bfhi(qa.w) + bfhi(qb.w));
    }
    if (tid < 72) w3s[tid] = cw3g[tid];
    __syncthreads();

    // conv1: [32,7,7] -> [16,14,14], k=4, s=2
    if (tid < 224) {
        const int co = tid / 14, y = tid % 14;
        float acc[14];
        const float bv = cb1g[co];
        #pragma unroll
        for (int x = 0; x < 14; ++x) acc[x] = bv;
        const int a0 = (y + 1) & 1;
        for (int aa = 0; aa < 2; ++aa) {
            const int a = a0 + 2 * aa;
            const int iy = (y + 1 - a) >> 1;
            if ((unsigned)iy < 7u) {
                #pragma unroll 2
                for (int ci = 0; ci < 32; ++ci) {
                    float rr[8];
                    *(float4*)&rr[0] = *(const float4*)&h2s[ci][iy][0];
                    *(float4*)&rr[4] = *(const float4*)&h2s[ci][iy][4];
                    const float4 w4 = *(const float4*)(cw1g + ci * 256 + co * 16 + a * 4);
                    const float wv[4] = {w4.x, w4.y, w4.z, w4.w};
                    #pragma unroll
                    for (int x = 0; x < 14; ++x) {
                        const int c0v = (x + 1) & 1;
                        const int ix0 = (x + 1 - c0v) >> 1;
                        if (ix0 < 7)  acc[x] += rr[ix0] * wv[c0v];
                        if (ix0 >= 1) acc[x] += rr[ix0 - 1] * wv[c0v + 2];
                    }
                }
            }
        }
        #pragma unroll
        for (int x = 0; x < 14; ++x) acc[x] = lrelu(acc[x]);
        *(float4*)&c1s[co][y][0]  = *(float4*)&acc[0];
        *(float4*)&c1s[co][y][4]  = *(float4*)&acc[4];
        *(float4*)&c1s[co][y][8]  = *(float4*)&acc[8];
        *(float2*)&c1s[co][y][12] = *(float2*)&acc[12];
    }
    __syncthreads();   // h2s dead beyond this point; c2s may now be written

    // conv2: [16,14,14] -> [8,28,28], k=4, s=2 — two register-light half passes
    if (tid < 224) {
        const int co = tid / 28, y = tid % 28;
        const float bv = cb2g[co];
        conv2_half<0>(c1s, c2s, cw2g, bv, co, y);
        conv2_half<1>(c1s, c2s, cw2g, bv, co, y);
    }
    __syncthreads();

    // conv3: [8,28,28] -> [1,28,28], k=3, s=1, tanh
    if (tid < 196) {
        const int y = tid / 7, q = tid % 7;
        const int xb = q * 4;
        float acc[4] = {cb3v, cb3v, cb3v, cb3v};
        for (int ci = 0; ci < 8; ++ci) {
            float wv[9];
            #pragma unroll
            for (int j = 0; j < 9; ++j) wv[j] = w3s[ci * 9 + j];
            #pragma unroll
            for (int a = 0; a < 3; ++a) {
                const int iy = y + 1 - a;
                if ((unsigned)iy < 28u) {
                    float rr[6];
                    #pragma unroll
                    for (int j = 0; j < 6; ++j) {
                        const int ix = xb - 1 + j;
                        rr[j] = ((unsigned)ix < 28u) ? bf1(c2s[ci][iy][ix]) : 0.f;
                    }
                    #pragma unroll
                    for (int xx = 0; xx < 4; ++xx)
                        #pragma unroll
                        for (int c = 0; c < 3; ++c)
                            acc[xx] += rr[xx + 2 - c] * wv[a * 3 + c];
                }
            }
        }
        float* op = out + (size_t)b * 784 + y * 28 + xb;
        #pragma unroll
        for (int xx = 0; xx < 4; ++xx) op[xx] = fast_tanh(acc[xx]);
    }
}

extern "C" void kernel_launch(void* const* d_in, const int* in_sizes, int n_in,
                              void* d_out, int out_size, void* d_ws, size_t ws_size,
                              hipStream_t stream) {
    const float* z   = (const float*)d_in[0];
    const int*   gi  = (const int*)d_in[1];
    const float* W1  = (const float*)d_in[2];
    const float* b1  = (const float*)d_in[3];
    const float* W2  = (const float*)d_in[4];
    const float* b2  = (const float*)d_in[5];
    const float* cw1 = (const float*)d_in[6];
    const float* cb1 = (const float*)d_in[7];
    const float* cw2 = (const float*)d_in[8];
    const float* cb2 = (const float*)d_in[9];
    const float* cw3 = (const float*)d_in[10];
    const float* cb3 = (const float*)d_in[11];
    int* wsi = (int*)d_ws;
    u16* h2g = (u16*)((char*)d_ws + WS_H2_OFF);   // 2 halves of 7.17 MB each

    bin_kernel<<<1, 256, 0, stream>>>(gi, wsi);
    fc_kernel<<<MAXG * NT * KS, 256, 0, stream>>>(z, gi, W1, b1, W2, b2, wsi, h2g);
    conv_kernel<<<BATCH, 256, 0, stream>>>(gi, cw1, cb1, cw2, cb2, cw3, cb3,
                                           h2g, (float*)d_out);
}